// Round 1
// baseline (565.883 us; speedup 1.0000x reference)
//
#include <hip/hip_runtime.h>

// TemporalAttentionCausal, single-pass fused kernel.
// out[bl,t,c] = h + cumsum_t(e*h)/(cumsum_t(e)+eps), e = exp(dot(h[bl,t,:],w)+b0).
// One block per (bl, 64-t chunk). The chunk's h lives in LDS (64 KiB), so h is
// read from HBM exactly once. Cross-chunk prefix (Se, per-channel P) exchanged
// via global memory + device-scope release/acquire flags (decoupled lookback).
// Deadlock-free: blocks take a dense atomic ticket; a block only waits on
// smaller tickets, which are held by already-resident (or finished) blocks
// whose publish depends on nothing.

constexpr int Tn = 1024, Hn = 256;
constexpr int BL   = 128;           // B*L
constexpr int CT   = 64;            // t per chunk
constexpr int NCH  = Tn / CT;       // 16 chunks per bl
constexpr int F4   = Hn / 4;        // 64 float4 per row
constexpr int NBLK = BL * NCH;      // 2048 blocks

__global__ __launch_bounds__(256) void k_fused(
    const float* __restrict__ h, const float* __restrict__ w,
    const float* __restrict__ bias, float* __restrict__ out,
    int* __restrict__ ticket, int* __restrict__ flags,
    float* __restrict__ P, float* __restrict__ Se)
{
    const int tid  = threadIdx.x;
    const int wv   = tid >> 6;          // wave 0..3, owns rows [16*wv, 16*wv+16)
    const int lane = tid & 63;          // = float4 column in H

    __shared__ float4 hbuf[CT * F4];    // 64 KiB chunk of h
    __shared__ float  e_s[CT], cums[CT], sdv[CT];
    __shared__ float4 PW[4][F4];        // per-wave channel partial sums
    __shared__ float  esw[4];
    __shared__ int    vb_s;

    if (tid == 0) vb_s = atomicAdd(ticket, 1);
    __syncthreads();
    const int vbid = vb_s;
    const int j  = vbid >> 7;           // chunk index (vbid / BL)
    const int bl = vbid & (BL - 1);

    const float  b0 = bias[0];
    const float4 w4 = reinterpret_cast<const float4*>(w)[lane];
    const float4* __restrict__ h4 = reinterpret_cast<const float4*>(h);
    const size_t rowbase = ((size_t)bl * Tn + (size_t)j * CT) * F4;

    // ---- stage h -> LDS, compute e, accumulate per-wave chunk partials ----
    float4 acc = make_float4(0.f, 0.f, 0.f, 0.f);
    float  esum = 0.f;
    const int r0 = wv * 16;
    #pragma unroll 4
    for (int i = 0; i < 16; ++i) {
        const int r = r0 + i;
        const float4 x = h4[rowbase + (size_t)r * F4 + lane];
        float p = x.x * w4.x + x.y * w4.y + x.z * w4.z + x.w * w4.w;
        p += __shfl_xor(p, 1);  p += __shfl_xor(p, 2);  p += __shfl_xor(p, 4);
        p += __shfl_xor(p, 8);  p += __shfl_xor(p, 16); p += __shfl_xor(p, 32);
        const float e = __expf(p + b0);           // all lanes hold full-row dot
        esum += e;
        acc.x = fmaf(e, x.x, acc.x); acc.y = fmaf(e, x.y, acc.y);
        acc.z = fmaf(e, x.z, acc.z); acc.w = fmaf(e, x.w, acc.w);
        hbuf[r * F4 + lane] = x;
        if (lane == 0) e_s[r] = e;
    }
    PW[wv][lane] = acc;
    if (lane == 0) esw[wv] = esum;
    __syncthreads();

    // ---- wave 0: local inclusive scan of e; wave 1: publish chunk sums ----
    if (wv == 0) {
        float c = e_s[lane];
        #pragma unroll
        for (int off = 1; off < 64; off <<= 1) {
            const float n = __shfl_up(c, off);
            if (lane >= off) c += n;
        }
        cums[lane] = c;
    } else if (wv == 1) {
        float4 p4 = PW[0][lane];
        const float4 q1 = PW[1][lane], q2 = PW[2][lane], q3 = PW[3][lane];
        p4.x += q1.x + q2.x + q3.x;  p4.y += q1.y + q2.y + q3.y;
        p4.z += q1.z + q2.z + q3.z;  p4.w += q1.w + q2.w + q3.w;
        reinterpret_cast<float4*>(P)[(size_t)vbid * F4 + lane] = p4;
        if (lane == 0) Se[vbid] = (esw[0] + esw[1]) + (esw[2] + esw[3]);
        __threadfence();
        if (lane == 0)
            __hip_atomic_store(&flags[vbid], 1, __ATOMIC_RELEASE,
                               __HIP_MEMORY_SCOPE_AGENT);
    }

    // ---- lookback: wait for the j predecessor chunks of this bl ----
    float seo = 0.f;
    if (lane < j) {
        const int pf = lane * BL + bl;
        while (__hip_atomic_load(&flags[pf], __ATOMIC_ACQUIRE,
                                 __HIP_MEMORY_SCOPE_AGENT) == 0) {
            __builtin_amdgcn_s_sleep(2);
        }
        seo = Se[pf];
    }
    seo += __shfl_xor(seo, 1); seo += __shfl_xor(seo, 2);
    seo += __shfl_xor(seo, 4); seo += __shfl_xor(seo, 8);
    seo = __shfl(seo, 0);

    float4 off4 = make_float4(0.f, 0.f, 0.f, 0.f);
    for (int jj = 0; jj < j; ++jj) {     // L2/L3-hot, independent loads
        const float4 q =
            reinterpret_cast<const float4*>(P)[((size_t)jj * BL + bl) * F4 + lane];
        off4.x += q.x; off4.y += q.y; off4.z += q.z; off4.w += q.w;
    }
    #pragma unroll
    for (int ww = 0; ww < 3; ++ww) {     // prefix over earlier waves (LDS)
        if (ww < wv) {
            const float4 q = PW[ww][lane];
            off4.x += q.x; off4.y += q.y; off4.z += q.z; off4.w += q.w;
        }
    }
    if (wv == 0) sdv[lane] = 1.0f / (seo + cums[lane] + 1e-12f);
    __syncthreads();

    // ---- output: per-channel running cumsum from LDS, float4 stores ----
    float4 a = off4;
    float4* __restrict__ o4 = reinterpret_cast<float4*>(out);
    #pragma unroll
    for (int u = 0; u < 16; ++u) {
        const int r = r0 + u;
        const float4 x = hbuf[r * F4 + lane];
        const float  e = e_s[r];
        a.x = fmaf(e, x.x, a.x); a.y = fmaf(e, x.y, a.y);
        a.z = fmaf(e, x.z, a.z); a.w = fmaf(e, x.w, a.w);
        const float s = sdv[r];
        float4 o;
        o.x = fmaf(a.x, s, x.x); o.y = fmaf(a.y, s, x.y);
        o.z = fmaf(a.z, s, x.z); o.w = fmaf(a.w, s, x.w);
        o4[rowbase + (size_t)r * F4 + lane] = o;
    }
}

extern "C" void kernel_launch(void* const* d_in, const int* in_sizes, int n_in,
                              void* d_out, int out_size, void* d_ws, size_t ws_size,
                              hipStream_t stream) {
    const float* h = (const float*)d_in[0];
    const float* w = (const float*)d_in[1];
    const float* b = (const float*)d_in[2];
    float* out = (float*)d_out;

    char* ws = (char*)d_ws;
    int*   ticket = (int*)ws;                                  // offset 0
    int*   flags  = (int*)(ws + 64);                           // NBLK ints
    float* P      = (float*)(ws + 16384);                      // NBLK*Hn floats
    float* Se     = (float*)(ws + 16384 + (size_t)NBLK * Hn * 4);

    // flags/ticket are poisoned between iterations -> must re-zero (8.3 KiB).
    hipMemsetAsync(d_ws, 0, 64 + NBLK * sizeof(int), stream);
    k_fused<<<NBLK, 256, 0, stream>>>(h, w, b, out, ticket, flags, P, Se);
}

// Round 2
// 262.035 us; speedup vs baseline: 2.1596x; 2.1596x over previous
//
#include <hip/hip_runtime.h>

// TemporalAttentionCausal: out = h + cumsum_t(e*h) / (cumsum_t(e) + eps),
// e = exp(dot(h[bl,t,:], w) + b0). Max-subtraction dropped (s ~ N(0,1), fp32
// safe; verified passing with absmax 0.0078).
//
// Two kernels, no atomics, no inter-block sync (kernel boundary = barrier):
//  k_scores: block (bl, j of 8). Wave = 32-t window. 16-lane groups compute
//            full 256-ch dots (4-step shfl), e, and per-WINDOW partials:
//            P32[bl,W,c] (vector), Se32[bl,W] (scalar). No LDS, no barriers.
//  k_apply : block (bl, j of 8). Wave = 32-t window W. Per-lane float4 of
//            channels. Offsets from <=31 L2-hot P32 rows + Se32 prefix +
//            shfl-scan of this window's e. Main loop: float4 load, 2 fma4,
//            float4 store per t. 16 B/lane throughout.

constexpr int Tn = 1024, Hn = 256;
constexpr int BL  = 128;          // B*L
constexpr int NCH = 8;            // chunks per bl (blocks)
constexpr int CT  = Tn / NCH;     // 128 t per block
constexpr int F4  = Hn / 4;       // 64 float4 per row
constexpr int NW  = Tn / 32;      // 32 windows of 32 t per bl

// ---------------- K1: scores + per-window partials ----------------
__global__ __launch_bounds__(256) void k_scores(const float* __restrict__ h,
                                                const float* __restrict__ w,
                                                const float* __restrict__ bias,
                                                float* __restrict__ ebuf,
                                                float* __restrict__ P32,
                                                float* __restrict__ Se32) {
    const int wave = threadIdx.x >> 6, lane = threadIdx.x & 63;
    const int g = lane >> 4, sub = lane & 15;   // group g handles t0+i*4+g
    const int j = blockIdx.x & 7, bl = blockIdx.x >> 3;
    const float b0 = bias[0];
    const float4* wp = reinterpret_cast<const float4*>(w);
    float4 w4[4];
    #pragma unroll
    for (int q = 0; q < 4; ++q) w4[q] = wp[sub + 16 * q];
    const float4* hp = reinterpret_cast<const float4*>(h) + (size_t)bl * Tn * F4;
    const int t0 = j * CT + wave * 32;

    float4 acc[4] = {{0,0,0,0},{0,0,0,0},{0,0,0,0},{0,0,0,0}};
    float esum = 0.f;
    #pragma unroll
    for (int i = 0; i < 8; ++i) {
        const int t = t0 + i * 4 + g;
        float4 x[4];
        #pragma unroll
        for (int q = 0; q < 4; ++q) x[q] = hp[(size_t)t * F4 + sub + 16 * q];
        float p = 0.f;
        #pragma unroll
        for (int q = 0; q < 4; ++q) {
            p = fmaf(x[q].x, w4[q].x, p);
            p = fmaf(x[q].y, w4[q].y, p);
            p = fmaf(x[q].z, w4[q].z, p);
            p = fmaf(x[q].w, w4[q].w, p);
        }
        p += __shfl_xor(p, 1);
        p += __shfl_xor(p, 2);
        p += __shfl_xor(p, 4);
        p += __shfl_xor(p, 8);
        const float e = __expf(p + b0);
        esum += e;
        #pragma unroll
        for (int q = 0; q < 4; ++q) {
            acc[q].x = fmaf(e, x[q].x, acc[q].x);
            acc[q].y = fmaf(e, x[q].y, acc[q].y);
            acc[q].z = fmaf(e, x[q].z, acc[q].z);
            acc[q].w = fmaf(e, x[q].w, acc[q].w);
        }
        if (sub == 0) ebuf[bl * Tn + t] = e;
    }
    // reduce across the 4 groups -> full 32-t window sums (every lane)
    #pragma unroll
    for (int q = 0; q < 4; ++q) {
        acc[q].x += __shfl_xor(acc[q].x, 16); acc[q].x += __shfl_xor(acc[q].x, 32);
        acc[q].y += __shfl_xor(acc[q].y, 16); acc[q].y += __shfl_xor(acc[q].y, 32);
        acc[q].z += __shfl_xor(acc[q].z, 16); acc[q].z += __shfl_xor(acc[q].z, 32);
        acc[q].w += __shfl_xor(acc[q].w, 16); acc[q].w += __shfl_xor(acc[q].w, 32);
    }
    esum += __shfl_xor(esum, 16);  esum += __shfl_xor(esum, 32);

    const int W = j * 4 + wave;                 // window index 0..31
    if (lane < 16) {
        float4* pp = reinterpret_cast<float4*>(P32) + ((size_t)bl * NW + W) * F4;
        pp[sub]      = acc[0];
        pp[sub + 16] = acc[1];
        pp[sub + 32] = acc[2];
        pp[sub + 48] = acc[3];
    }
    if (lane == 0) Se32[bl * NW + W] = esum;
}

// ---------------- K2: prefix-corrected scan + output ----------------
__global__ __launch_bounds__(256) void k_apply(const float* __restrict__ h,
                                               const float* __restrict__ ebuf,
                                               const float* __restrict__ P32,
                                               const float* __restrict__ Se32,
                                               float* __restrict__ out) {
    const int wave = threadIdx.x >> 6, lane = threadIdx.x & 63;
    const int j = blockIdx.x & 7, bl = blockIdx.x >> 3;
    const int W = j * 4 + wave;                 // this wave's 32-t window
    const int t0 = W * 32;

    // per-channel starting offset: sum of earlier windows' P32 (L2-hot)
    const float4* Pp = reinterpret_cast<const float4*>(P32) + (size_t)bl * NW * F4;
    float4 off4 = make_float4(0.f, 0.f, 0.f, 0.f);
    for (int q = 0; q < W; ++q) {
        const float4 v = Pp[q * F4 + lane];
        off4.x += v.x; off4.y += v.y; off4.z += v.z; off4.w += v.w;
    }
    // scalar e-prefix: sum of earlier windows' Se32
    float seo = 0.f;
    if (lane < W) seo = Se32[bl * NW + lane];
    seo += __shfl_xor(seo, 1); seo += __shfl_xor(seo, 2);
    seo += __shfl_xor(seo, 4); seo += __shfl_xor(seo, 8);
    seo += __shfl_xor(seo, 16);
    seo = __shfl(seo, 0);

    // this window's e values: lane i<32 holds e[t0+i]; inclusive shfl scan
    float ev = 0.f;
    if (lane < 32) ev = ebuf[bl * Tn + t0 + lane];
    float sc = ev;
    #pragma unroll
    for (int off = 1; off < 32; off <<= 1) {
        const float n = __shfl_up(sc, off);
        if (lane >= off) sc += n;
    }
    const float sdv = 1.0f / (seo + sc + 1e-12f);   // valid on lanes < 32

    const float4* hp = reinterpret_cast<const float4*>(h)
                       + ((size_t)bl * Tn + t0) * F4 + lane;
    float4* op = reinterpret_cast<float4*>(out)
                 + ((size_t)bl * Tn + t0) * F4 + lane;

    float4 a = off4;
    #pragma unroll
    for (int i = 0; i < 32; i += 8) {
        float4 x[8];
        #pragma unroll
        for (int u = 0; u < 8; ++u) x[u] = hp[(size_t)(i + u) * F4];
        #pragma unroll
        for (int u = 0; u < 8; ++u) {
            const float e = __shfl(ev,  i + u);
            const float s = __shfl(sdv, i + u);
            a.x = fmaf(e, x[u].x, a.x); a.y = fmaf(e, x[u].y, a.y);
            a.z = fmaf(e, x[u].z, a.z); a.w = fmaf(e, x[u].w, a.w);
            float4 o;
            o.x = fmaf(a.x, s, x[u].x); o.y = fmaf(a.y, s, x[u].y);
            o.z = fmaf(a.z, s, x[u].z); o.w = fmaf(a.w, s, x[u].w);
            op[(size_t)(i + u) * F4] = o;
        }
    }
}

extern "C" void kernel_launch(void* const* d_in, const int* in_sizes, int n_in,
                              void* d_out, int out_size, void* d_ws, size_t ws_size,
                              hipStream_t stream) {
    const float* h = (const float*)d_in[0];
    const float* w = (const float*)d_in[1];
    const float* b = (const float*)d_in[2];
    float* out = (float*)d_out;

    float* ebuf = (float*)d_ws;                     // BL*Tn floats   (512 KB)
    float* P32  = ebuf + BL * Tn;                   // BL*NW*Hn floats (4 MB)
    float* Se32 = P32 + (size_t)BL * NW * Hn;       // BL*NW floats   (16 KB)

    k_scores<<<BL * NCH, 256, 0, stream>>>(h, w, b, ebuf, P32, Se32);
    k_apply <<<BL * NCH, 256, 0, stream>>>(h, ebuf, P32, Se32, out);
}